// Round 6
// baseline (1571.177 us; speedup 1.0000x reference)
//
#include <hip/hip_runtime.h>
#include <cstddef>

#define L_SEQ 1024
#define B_SZ  128
#define D_SZ  256
#define H_SZ  256

#define NGEMM 128            // producer blocks (bid 0..127), dispatched FIRST
#define NSCAN 128            // consumer blocks (bid 128..255)
#define KT    16
#define LDA   132
#define SLICE_W 40

typedef float f2 __attribute__((ext_vector_type(2)));

// ---------------------------------------------------------------------------
// Fused producer-consumer kernel, v2 (R3 retry with HARD CU PARTITIONING).
// R3 failed because GEMM blocks co-resident on scan CUs serialized the scan's
// LDS handoff (4.2M bank conflicts). Fix: 512-thread blocks +
// amdgpu_waves_per_eu(2,2) -> 8 waves = exactly 1 block/CU; grid=256 blocks
// on 256 CUs -> roles never share a CU.
// Deadlock-safe: GEMM blocks have lower blockIdx (dispatched first) and never
// wait on scan blocks; scan blocks spin on done[] which GEMM sets regardless.
// Coherence (R3-proven): GEMM stores + __threadfence_system + release-add to
// done[tm]; scan reads done[] and xproj with RELAXED SYSTEM-scope loads
// (bypass possibly-stale per-XCD L2; no vmcnt(0)-draining acquire on the
// scan critical path).
// GEMM inner loop: scalar v_fmac (v_pk_fma_f32 is HALF-RATE for fp32 --
// R5 lesson: pk peak == scalar peak 157TF; pk+inline-asm regressed 290->360us).
// ---------------------------------------------------------------------------

#define PKFMA(acc, w, h) \
    asm("v_pk_fma_f32 %0, %1, %2, %0" : "+v"(acc) : "v"(w), "v"(h))

template <int CTRL>
__device__ __forceinline__ float dpp_add(float v) {
    int y = __builtin_amdgcn_mov_dpp(__float_as_int(v), CTRL, 0xf, 0xf, true);
    return v + __int_as_float(y);
}
// Full butterfly over the 8 lanes of a ks-group (pure VALU, valid all lanes).
__device__ __forceinline__ float red8(f2 a) {
    float v = a.x + a.y;
    v = dpp_add<0xB1>(v);     // quad_perm xor 1
    v = dpp_add<0x4E>(v);     // quad_perm xor 2
    v = dpp_add<0x141>(v);    // row_half_mirror (xor 7)
    return v;
}
__device__ __forceinline__ float fast_tanh(float x) {
    float e = __expf(2.0f * x);
    return 1.0f - 2.0f * __builtin_amdgcn_rcpf(e + 1.0f);
}
// Barrier that does NOT drain vmcnt: only LDS ordering is required.
__device__ __forceinline__ void lds_barrier() {
    asm volatile("s_waitcnt lgkmcnt(0)" ::: "memory");
    __builtin_amdgcn_s_barrier();
    asm volatile("" ::: "memory");
}
__device__ __forceinline__ float sysloadf(const float* p) {
    return __hip_atomic_load(p, __ATOMIC_RELAXED, __HIP_MEMORY_SCOPE_SYSTEM);
}
__device__ __forceinline__ int sysloadi(const int* p) {
    return __hip_atomic_load(p, __ATOMIC_RELAXED, __HIP_MEMORY_SCOPE_SYSTEM);
}

// ---------------------------------------------------------------------------
// GEMM role: 512 threads, 128x128 tile, KT=16, 16 tiles per block in
// time-order (pass p covers tileIdx p*128+gb -> tm rises monotonically).
// Per-thread microtile 4 rows x (4+4) cols; bn0/bn1 at tx*4 / 64+tx*4 keeps
// LDS reads at worst 2-way aliased (free).
// ---------------------------------------------------------------------------
__device__ __forceinline__ void gemm_role(
    int gb,
    const float* __restrict__ x, const float* __restrict__ Wx,
    const float* __restrict__ bx, const float* __restrict__ bh,
    float* __restrict__ out, int* __restrict__ done,
    float (*sA)[LDA], float (*sB)[LDA])
{
    const int tid  = threadIdx.x;
    const int tx   = tid & 15;       // col quad 0..15
    const int ty   = tid >> 4;       // row quad 0..31
    const int srow = tid >> 2;       // 0..127 (stage row)
    const int skq  = tid & 3;        // 0..3   (stage k-quad)

    for (int pass = 0; pass < 16; ++pass) {
        const int tileIdx = pass * NGEMM + gb;
        const int tm = tileIdx >> 1;
        const int tn = tileIdx & 1;

        const float* __restrict__ Ag = x  + (size_t)(tm * 128 + srow) * D_SZ + skq * 4;
        const float* __restrict__ Bg = Wx + (size_t)(tn * 128 + srow) * D_SZ + skq * 4;

        float c[2][4][4];
        #pragma unroll
        for (int nc = 0; nc < 2; ++nc)
            #pragma unroll
            for (int i = 0; i < 4; ++i)
                #pragma unroll
                for (int j = 0; j < 4; ++j) c[nc][i][j] = 0.0f;

        for (int kt = 0; kt < D_SZ / KT; ++kt) {
            float4 av = *reinterpret_cast<const float4*>(Ag + kt * KT);
            float4 bv = *reinterpret_cast<const float4*>(Bg + kt * KT);
            __syncthreads();
            sA[skq * 4 + 0][srow] = av.x; sA[skq * 4 + 1][srow] = av.y;
            sA[skq * 4 + 2][srow] = av.z; sA[skq * 4 + 3][srow] = av.w;
            sB[skq * 4 + 0][srow] = bv.x; sB[skq * 4 + 1][srow] = bv.y;
            sB[skq * 4 + 2][srow] = bv.z; sB[skq * 4 + 3][srow] = bv.w;
            __syncthreads();
            #pragma unroll
            for (int kk = 0; kk < KT; ++kk) {
                float4 am  = *reinterpret_cast<const float4*>(&sA[kk][ty * 4]);
                float4 bn0 = *reinterpret_cast<const float4*>(&sB[kk][tx * 4]);
                float4 bn1 = *reinterpret_cast<const float4*>(&sB[kk][64 + tx * 4]);
                float aa[4] = {am.x, am.y, am.z, am.w};
                float bb[2][4] = {{bn0.x, bn0.y, bn0.z, bn0.w},
                                  {bn1.x, bn1.y, bn1.z, bn1.w}};
                #pragma unroll
                for (int nc = 0; nc < 2; ++nc)
                    #pragma unroll
                    for (int i = 0; i < 4; ++i)
                        #pragma unroll
                        for (int j = 0; j < 4; ++j)
                            c[nc][i][j] = fmaf(aa[i], bb[nc][j], c[nc][i][j]);
            }
        }

        #pragma unroll
        for (int nc = 0; nc < 2; ++nc) {
            const int col = tn * 128 + nc * 64 + tx * 4;
            float4 b4 = *reinterpret_cast<const float4*>(bx + col);
            float4 h4 = *reinterpret_cast<const float4*>(bh + col);  // fold Wh bias
            #pragma unroll
            for (int i = 0; i < 4; ++i) {
                float4 v;
                v.x = c[nc][i][0] + b4.x + h4.x;
                v.y = c[nc][i][1] + b4.y + h4.y;
                v.z = c[nc][i][2] + b4.z + h4.z;
                v.w = c[nc][i][3] + b4.w + h4.w;
                *reinterpret_cast<float4*>(
                    out + (size_t)(tm * 128 + ty * 4 + i) * H_SZ + col) = v;
            }
        }

        // Publish: data ordered to L3/HBM, then flag (2 increments per tm).
        __threadfence_system();
        __syncthreads();
        if (tid == 0) {
            __hip_atomic_fetch_add(&done[tm], 1, __ATOMIC_RELEASE,
                                   __HIP_MEMORY_SCOPE_SYSTEM);
        }
    }
}

// ---------------------------------------------------------------------------
// Scan role (R3's polling scan, verbatim protocol -- it PASSED; only the CU
// interference was the problem, now removed by partitioning).
// ---------------------------------------------------------------------------
#define DECLQ(c, q) \
    f2 w##c##_##q##l = r##c[2 * (q)], w##c##_##q##h = r##c[2 * (q) + 1];
#define DECLC(c) \
    DECLQ(c,0) DECLQ(c,1) DECLQ(c,2) DECLQ(c,3) \
    DECLQ(c,4) DECLQ(c,5) DECLQ(c,6) DECLQ(c,7)

#define FMAQ(q) { \
    float4 hv = hv4[q]; \
    f2 hlo = {hv.x, hv.y}; \
    f2 hhi = {hv.z, hv.w}; \
    PKFMA(a0, w0_##q##l, hlo); PKFMA(a0, w0_##q##h, hhi); \
    PKFMA(a1, w1_##q##l, hlo); PKFMA(a1, w1_##q##h, hhi); \
    PKFMA(a2, w2_##q##l, hlo); PKFMA(a2, w2_##q##h, hhi); \
    PKFMA(a3, w3_##q##l, hlo); PKFMA(a3, w3_##q##h, hhi); }

// One scan step. Poll protocol (R3):
//  - apply lookahead flag results issued LAST body (loads ~1 body old)
//  - cold spin only if still behind (steady state: scalar compare only)
//  - issue NEXT lookahead polls, then the t+2 xp prefetch (system-scope)
#define SBODY(T, SRC, DST, X0, X1, X2, X3) { \
    if (la0 == 2) { ++hw; if (la1 == 2) ++hw; } \
    const int tnext = ((T) + 2 < L_SEQ) ? (T) + 2 : L_SEQ - 1; \
    { const int need = tnext + 1; \
      while (hw < need) { \
        int d = sysloadi(&done[hw]); \
        if (d == 2) ++hw; else __builtin_amdgcn_s_sleep(2); \
      } } \
    asm volatile("" ::: "memory"); \
    la0 = 0; la1 = 0; \
    if (hw < L_SEQ)     la0 = sysloadi(&done[hw]); \
    if (hw + 1 < L_SEQ) la1 = sysloadi(&done[hw + 1]); \
    float u0 = X0, u1 = X1, u2 = X2, u3 = X3; \
    { const size_t t2 = (size_t)tnext * tstr; \
      X0 = sysloadf(&outb[t2 + jg +   0]); \
      X1 = sysloadf(&outb[t2 + jg +  64]); \
      X2 = sysloadf(&outb[t2 + jg + 128]); \
      X3 = sysloadf(&outb[t2 + jg + 192]); } \
    f2 a0 = {0.f, 0.f}, a1 = {0.f, 0.f}, a2 = {0.f, 0.f}, a3 = {0.f, 0.f}; \
    const float4* hv4 = reinterpret_cast<const float4*>(&hs[SRC][ks * SLICE_W]); \
    FMAQ(0) FMAQ(1) FMAQ(2) FMAQ(3) FMAQ(4) FMAQ(5) FMAQ(6) FMAQ(7) \
    float s0 = red8(a0); \
    float s1 = red8(a1); \
    float s2 = red8(a2); \
    float s3 = red8(a3); \
    hn0 = fast_tanh(u0 + s0); \
    hn1 = fast_tanh(u1 + s1); \
    hn2 = fast_tanh(u2 + s2); \
    hn3 = fast_tanh(u3 + s3); \
    if (ks == 0) { \
        const size_t tb = (size_t)(T) * tstr; \
        __builtin_nontemporal_store(hn0, &outb[tb + jg +   0]); \
        __builtin_nontemporal_store(hn1, &outb[tb + jg +  64]); \
        __builtin_nontemporal_store(hn2, &outb[tb + jg + 128]); \
        __builtin_nontemporal_store(hn3, &outb[tb + jg + 192]); \
        float* hptr = hs[DST]; \
        const int base = (jg >> 5) * SLICE_W + (jg & 31); \
        hptr[base + 0 * (2 * SLICE_W)] = hn0; \
        hptr[base + 1 * (2 * SLICE_W)] = hn1; \
        hptr[base + 2 * (2 * SLICE_W)] = hn2; \
        hptr[base + 3 * (2 * SLICE_W)] = hn3; \
    } \
    lds_barrier(); \
}

__device__ __forceinline__ void scan_role(
    int b,
    const float* __restrict__ h0, const float* __restrict__ Wh,
    float* __restrict__ out, int* __restrict__ done,
    float (*hs)[8 * SLICE_W])
{
    const int tid  = threadIdx.x;
    const int lane = tid & 63;
    const int wave = tid >> 6;
    const int ks   = lane & 7;                 // K slice 0..7
    const int jg   = wave * 8 + (lane >> 3);   // channel group 0..63

    const f2* r0 = reinterpret_cast<const f2*>(Wh + (size_t)(jg +   0) * H_SZ + ks * 32);
    const f2* r1 = reinterpret_cast<const f2*>(Wh + (size_t)(jg +  64) * H_SZ + ks * 32);
    const f2* r2 = reinterpret_cast<const f2*>(Wh + (size_t)(jg + 128) * H_SZ + ks * 32);
    const f2* r3 = reinterpret_cast<const f2*>(Wh + (size_t)(jg + 192) * H_SZ + ks * 32);
    DECLC(0) DECLC(1) DECLC(2) DECLC(3)

    if (tid < H_SZ) {
        hs[0][(tid >> 5) * SLICE_W + (tid & 31)] = h0[(size_t)b * H_SZ + tid];
    }
    __syncthreads();

    float* __restrict__ outb = out + (size_t)b * H_SZ;
    const size_t tstr = (size_t)B_SZ * H_SZ;

    int hw = 0, la0 = 0, la1 = 0;
    // cold-start: need slabs 0,1 for prologue loads
    while (hw < 2) {
        int d = sysloadi(&done[hw]);
        if (d == 2) ++hw; else __builtin_amdgcn_s_sleep(8);
    }
    asm volatile("" ::: "memory");

    float xa0 = sysloadf(&outb[jg +   0]);
    float xa1 = sysloadf(&outb[jg +  64]);
    float xa2 = sysloadf(&outb[jg + 128]);
    float xa3 = sysloadf(&outb[jg + 192]);
    float xb0 = sysloadf(&outb[tstr + jg +   0]);
    float xb1 = sysloadf(&outb[tstr + jg +  64]);
    float xb2 = sysloadf(&outb[tstr + jg + 128]);
    float xb3 = sysloadf(&outb[tstr + jg + 192]);

    float hn0 = 0.f, hn1 = 0.f, hn2 = 0.f, hn3 = 0.f;
    for (int t = 0; t < L_SEQ; t += 2) {
        SBODY(t,     0, 1, xa0, xa1, xa2, xa3)
        SBODY(t + 1, 1, 0, xb0, xb1, xb2, xb3)
    }

    if (ks == 0) {
        float* hf = out + (size_t)L_SEQ * tstr + (size_t)b * H_SZ;
        hf[jg +   0] = hn0;
        hf[jg +  64] = hn1;
        hf[jg + 128] = hn2;
        hf[jg + 192] = hn3;
    }
}

// ---------------------------------------------------------------------------
// Fused kernel: 256 blocks x 512 threads, waves_per_eu(2,2) -> 1 block/CU.
// ---------------------------------------------------------------------------
__global__ __launch_bounds__(512)
__attribute__((amdgpu_waves_per_eu(2, 2)))
void rnn_fused(
    const float* __restrict__ x,  const float* __restrict__ h0,
    const float* __restrict__ Wx, const float* __restrict__ bx,
    const float* __restrict__ Wh, const float* __restrict__ bh,
    float* __restrict__ out, int* __restrict__ done)
{
    __shared__ float sA[KT][LDA];
    __shared__ float sB[KT][LDA];
    __shared__ __align__(16) float hs[2][8 * SLICE_W];

    const int bid = blockIdx.x;
    if (bid < NGEMM) {
        gemm_role(bid, x, Wx, bx, bh, out, done, sA, sB);
    } else {
        scan_role(bid - NGEMM, h0, Wh, out, done, hs);
    }
}

extern "C" void kernel_launch(void* const* d_in, const int* in_sizes, int n_in,
                              void* d_out, int out_size, void* d_ws, size_t ws_size,
                              hipStream_t stream) {
    const float* x    = (const float*)d_in[0];   // [L,B,D]
    const float* h0   = (const float*)d_in[1];   // [B,H]
    const float* Wx_w = (const float*)d_in[2];   // [H,D]
    const float* Wx_b = (const float*)d_in[3];   // [H]
    const float* Wh_w = (const float*)d_in[4];   // [H,H]
    const float* Wh_b = (const float*)d_in[5];   // [H]
    float* out = (float*)d_out;                  // [L,B,H] ++ [B,H]
    int* done = (int*)d_ws;                      // [L_SEQ] tile-completion flags

    (void)in_sizes; (void)n_in; (void)ws_size; (void)out_size;

    // Re-arm flags every iteration (graph-safe stream op).
    hipMemsetAsync(done, 0, L_SEQ * sizeof(int), stream);

    rnn_fused<<<dim3(NGEMM + NSCAN), 512, 0, stream>>>(
        x, h0, Wx_w, Wx_b, Wh_w, Wh_b, out, done);
}

// Round 7
// 1111.069 us; speedup vs baseline: 1.4141x; 1.4141x over previous
//
#include <hip/hip_runtime.h>
#include <cstddef>
#include <cstdint>

#define L_SEQ 1024
#define B_SZ  128
#define D_SZ  256
#define H_SZ  256

#define NGEMM 128            // producer blocks (bid 0..127), dispatched FIRST
#define NSCAN 128            // consumer blocks (bid 128..255)
#define KT    16
#define LDA   132
#define SLICE_W 40

typedef float f2 __attribute__((ext_vector_type(2)));

// ---------------------------------------------------------------------------
// Fused producer-consumer kernel, v3: FENCELESS PUBLICATION.
// R3/R6 both stalled at ~1490us with identical counters; the shared structure
// was __threadfence_system PER TILE (2048 buffer_wbl2 + vmcnt drains) which
// throttled the producers. v3 removes all cache maintenance:
//  - producer epilogue stores are SYSTEM-scope RELAXED 8B atomic stores
//    (write-through sc0 sc1 -> land in L3, no dirty-L2 copy, nothing to flush)
//  - __syncthreads() drains vmcnt for every thread (stores retired = visible)
//  - flag is a RELAXED system fetch_add (no release fence needed)
//  - consumer (unchanged, proven): RELAXED system loads bypass stale L2s.
// Bank conflicts (4.2M) are GEMM-intrinsic (2048/tile deterministic) and
// performance-irrelevant -- not interference (R6 disproof).
// ---------------------------------------------------------------------------

#define PKFMA(acc, w, h) \
    asm("v_pk_fma_f32 %0, %1, %2, %0" : "+v"(acc) : "v"(w), "v"(h))

template <int CTRL>
__device__ __forceinline__ float dpp_add(float v) {
    int y = __builtin_amdgcn_mov_dpp(__float_as_int(v), CTRL, 0xf, 0xf, true);
    return v + __int_as_float(y);
}
// Full butterfly over the 8 lanes of a ks-group (pure VALU, valid all lanes).
__device__ __forceinline__ float red8(f2 a) {
    float v = a.x + a.y;
    v = dpp_add<0xB1>(v);     // quad_perm xor 1
    v = dpp_add<0x4E>(v);     // quad_perm xor 2
    v = dpp_add<0x141>(v);    // row_half_mirror (xor 7)
    return v;
}
__device__ __forceinline__ float fast_tanh(float x) {
    float e = __expf(2.0f * x);
    return 1.0f - 2.0f * __builtin_amdgcn_rcpf(e + 1.0f);
}
// Barrier that does NOT drain vmcnt: only LDS ordering is required.
__device__ __forceinline__ void lds_barrier() {
    asm volatile("s_waitcnt lgkmcnt(0)" ::: "memory");
    __builtin_amdgcn_s_barrier();
    asm volatile("" ::: "memory");
}
__device__ __forceinline__ float sysloadf(const float* p) {
    return __hip_atomic_load(p, __ATOMIC_RELAXED, __HIP_MEMORY_SCOPE_SYSTEM);
}
__device__ __forceinline__ int sysloadi(const int* p) {
    return __hip_atomic_load(p, __ATOMIC_RELAXED, __HIP_MEMORY_SCOPE_SYSTEM);
}
__device__ __forceinline__ void sysstore8(float* p, float a, float b) {
    float2 v; v.x = a; v.y = b;
    __hip_atomic_store(reinterpret_cast<uint64_t*>(p),
                       __builtin_bit_cast(uint64_t, v),
                       __ATOMIC_RELAXED, __HIP_MEMORY_SCOPE_SYSTEM);
}

// ---------------------------------------------------------------------------
// GEMM role: 512 threads, 128x128 tile, KT=16, 16 tiles per block in
// time-order (pass p covers tileIdx p*128+gb -> tm rises monotonically).
// ---------------------------------------------------------------------------
__device__ __forceinline__ void gemm_role(
    int gb,
    const float* __restrict__ x, const float* __restrict__ Wx,
    const float* __restrict__ bx, const float* __restrict__ bh,
    float* __restrict__ out, int* __restrict__ done,
    float (*sA)[LDA], float (*sB)[LDA])
{
    const int tid  = threadIdx.x;
    const int tx   = tid & 15;       // col quad 0..15
    const int ty   = tid >> 4;       // row quad 0..31
    const int srow = tid >> 2;       // 0..127 (stage row)
    const int skq  = tid & 3;        // 0..3   (stage k-quad)

    for (int pass = 0; pass < 16; ++pass) {
        const int tileIdx = pass * NGEMM + gb;
        const int tm = tileIdx >> 1;
        const int tn = tileIdx & 1;

        const float* __restrict__ Ag = x  + (size_t)(tm * 128 + srow) * D_SZ + skq * 4;
        const float* __restrict__ Bg = Wx + (size_t)(tn * 128 + srow) * D_SZ + skq * 4;

        float c[2][4][4];
        #pragma unroll
        for (int nc = 0; nc < 2; ++nc)
            #pragma unroll
            for (int i = 0; i < 4; ++i)
                #pragma unroll
                for (int j = 0; j < 4; ++j) c[nc][i][j] = 0.0f;

        for (int kt = 0; kt < D_SZ / KT; ++kt) {
            float4 av = *reinterpret_cast<const float4*>(Ag + kt * KT);
            float4 bv = *reinterpret_cast<const float4*>(Bg + kt * KT);
            __syncthreads();
            sA[skq * 4 + 0][srow] = av.x; sA[skq * 4 + 1][srow] = av.y;
            sA[skq * 4 + 2][srow] = av.z; sA[skq * 4 + 3][srow] = av.w;
            sB[skq * 4 + 0][srow] = bv.x; sB[skq * 4 + 1][srow] = bv.y;
            sB[skq * 4 + 2][srow] = bv.z; sB[skq * 4 + 3][srow] = bv.w;
            __syncthreads();
            #pragma unroll
            for (int kk = 0; kk < KT; ++kk) {
                float4 am  = *reinterpret_cast<const float4*>(&sA[kk][ty * 4]);
                float4 bn0 = *reinterpret_cast<const float4*>(&sB[kk][tx * 4]);
                float4 bn1 = *reinterpret_cast<const float4*>(&sB[kk][64 + tx * 4]);
                float aa[4] = {am.x, am.y, am.z, am.w};
                float bb[2][4] = {{bn0.x, bn0.y, bn0.z, bn0.w},
                                  {bn1.x, bn1.y, bn1.z, bn1.w}};
                #pragma unroll
                for (int nc = 0; nc < 2; ++nc)
                    #pragma unroll
                    for (int i = 0; i < 4; ++i)
                        #pragma unroll
                        for (int j = 0; j < 4; ++j)
                            c[nc][i][j] = fmaf(aa[i], bb[nc][j], c[nc][i][j]);
            }
        }

        // Epilogue: write-through system stores (no L2-dirty data, no wbl2).
        #pragma unroll
        for (int nc = 0; nc < 2; ++nc) {
            const int col = tn * 128 + nc * 64 + tx * 4;
            float4 b4 = *reinterpret_cast<const float4*>(bx + col);
            float4 h4 = *reinterpret_cast<const float4*>(bh + col);  // fold Wh bias
            #pragma unroll
            for (int i = 0; i < 4; ++i) {
                float* dst = out + (size_t)(tm * 128 + ty * 4 + i) * H_SZ + col;
                sysstore8(dst,     c[nc][i][0] + b4.x + h4.x,
                                   c[nc][i][1] + b4.y + h4.y);
                sysstore8(dst + 2, c[nc][i][2] + b4.z + h4.z,
                                   c[nc][i][3] + b4.w + h4.w);
            }
        }

        // __syncthreads drains each thread's vmcnt (write-through stores
        // retired => L3-visible), then one relaxed flag increment.
        __syncthreads();
        if (tid == 0) {
            __hip_atomic_fetch_add(&done[tm], 1, __ATOMIC_RELAXED,
                                   __HIP_MEMORY_SCOPE_SYSTEM);
        }
    }
}

// ---------------------------------------------------------------------------
// Scan role (R3/R6-proven polling protocol, unchanged).
// ---------------------------------------------------------------------------
#define DECLQ(c, q) \
    f2 w##c##_##q##l = r##c[2 * (q)], w##c##_##q##h = r##c[2 * (q) + 1];
#define DECLC(c) \
    DECLQ(c,0) DECLQ(c,1) DECLQ(c,2) DECLQ(c,3) \
    DECLQ(c,4) DECLQ(c,5) DECLQ(c,6) DECLQ(c,7)

#define FMAQ(q) { \
    float4 hv = hv4[q]; \
    f2 hlo = {hv.x, hv.y}; \
    f2 hhi = {hv.z, hv.w}; \
    PKFMA(a0, w0_##q##l, hlo); PKFMA(a0, w0_##q##h, hhi); \
    PKFMA(a1, w1_##q##l, hlo); PKFMA(a1, w1_##q##h, hhi); \
    PKFMA(a2, w2_##q##l, hlo); PKFMA(a2, w2_##q##h, hhi); \
    PKFMA(a3, w3_##q##l, hlo); PKFMA(a3, w3_##q##h, hhi); }

// One scan step. Poll protocol:
//  - apply lookahead flag results issued LAST body (loads ~1 body old)
//  - cold spin only if still behind (steady state: scalar compare only)
//  - issue NEXT lookahead polls, then the t+2 xp prefetch (system-scope)
#define SBODY(T, SRC, DST, X0, X1, X2, X3) { \
    if (la0 == 2) { ++hw; if (la1 == 2) ++hw; } \
    const int tnext = ((T) + 2 < L_SEQ) ? (T) + 2 : L_SEQ - 1; \
    { const int need = tnext + 1; \
      while (hw < need) { \
        int d = sysloadi(&done[hw]); \
        if (d == 2) ++hw; else __builtin_amdgcn_s_sleep(2); \
      } } \
    asm volatile("" ::: "memory"); \
    la0 = 0; la1 = 0; \
    if (hw < L_SEQ)     la0 = sysloadi(&done[hw]); \
    if (hw + 1 < L_SEQ) la1 = sysloadi(&done[hw + 1]); \
    float u0 = X0, u1 = X1, u2 = X2, u3 = X3; \
    { const size_t t2 = (size_t)tnext * tstr; \
      X0 = sysloadf(&outb[t2 + jg +   0]); \
      X1 = sysloadf(&outb[t2 + jg +  64]); \
      X2 = sysloadf(&outb[t2 + jg + 128]); \
      X3 = sysloadf(&outb[t2 + jg + 192]); } \
    f2 a0 = {0.f, 0.f}, a1 = {0.f, 0.f}, a2 = {0.f, 0.f}, a3 = {0.f, 0.f}; \
    const float4* hv4 = reinterpret_cast<const float4*>(&hs[SRC][ks * SLICE_W]); \
    FMAQ(0) FMAQ(1) FMAQ(2) FMAQ(3) FMAQ(4) FMAQ(5) FMAQ(6) FMAQ(7) \
    float s0 = red8(a0); \
    float s1 = red8(a1); \
    float s2 = red8(a2); \
    float s3 = red8(a3); \
    hn0 = fast_tanh(u0 + s0); \
    hn1 = fast_tanh(u1 + s1); \
    hn2 = fast_tanh(u2 + s2); \
    hn3 = fast_tanh(u3 + s3); \
    if (ks == 0) { \
        const size_t tb = (size_t)(T) * tstr; \
        __builtin_nontemporal_store(hn0, &outb[tb + jg +   0]); \
        __builtin_nontemporal_store(hn1, &outb[tb + jg +  64]); \
        __builtin_nontemporal_store(hn2, &outb[tb + jg + 128]); \
        __builtin_nontemporal_store(hn3, &outb[tb + jg + 192]); \
        float* hptr = hs[DST]; \
        const int base = (jg >> 5) * SLICE_W + (jg & 31); \
        hptr[base + 0 * (2 * SLICE_W)] = hn0; \
        hptr[base + 1 * (2 * SLICE_W)] = hn1; \
        hptr[base + 2 * (2 * SLICE_W)] = hn2; \
        hptr[base + 3 * (2 * SLICE_W)] = hn3; \
    } \
    lds_barrier(); \
}

__device__ __forceinline__ void scan_role(
    int b,
    const float* __restrict__ h0, const float* __restrict__ Wh,
    float* __restrict__ out, int* __restrict__ done,
    float (*hs)[8 * SLICE_W])
{
    const int tid  = threadIdx.x;
    const int lane = tid & 63;
    const int wave = tid >> 6;
    const int ks   = lane & 7;                 // K slice 0..7
    const int jg   = wave * 8 + (lane >> 3);   // channel group 0..63

    const f2* r0 = reinterpret_cast<const f2*>(Wh + (size_t)(jg +   0) * H_SZ + ks * 32);
    const f2* r1 = reinterpret_cast<const f2*>(Wh + (size_t)(jg +  64) * H_SZ + ks * 32);
    const f2* r2 = reinterpret_cast<const f2*>(Wh + (size_t)(jg + 128) * H_SZ + ks * 32);
    const f2* r3 = reinterpret_cast<const f2*>(Wh + (size_t)(jg + 192) * H_SZ + ks * 32);
    DECLC(0) DECLC(1) DECLC(2) DECLC(3)

    if (tid < H_SZ) {
        hs[0][(tid >> 5) * SLICE_W + (tid & 31)] = h0[(size_t)b * H_SZ + tid];
    }
    __syncthreads();

    float* __restrict__ outb = out + (size_t)b * H_SZ;
    const size_t tstr = (size_t)B_SZ * H_SZ;

    int hw = 0, la0 = 0, la1 = 0;
    // cold-start: need slabs 0,1 for prologue loads
    while (hw < 2) {
        int d = sysloadi(&done[hw]);
        if (d == 2) ++hw; else __builtin_amdgcn_s_sleep(8);
    }
    asm volatile("" ::: "memory");

    float xa0 = sysloadf(&outb[jg +   0]);
    float xa1 = sysloadf(&outb[jg +  64]);
    float xa2 = sysloadf(&outb[jg + 128]);
    float xa3 = sysloadf(&outb[jg + 192]);
    float xb0 = sysloadf(&outb[tstr + jg +   0]);
    float xb1 = sysloadf(&outb[tstr + jg +  64]);
    float xb2 = sysloadf(&outb[tstr + jg + 128]);
    float xb3 = sysloadf(&outb[tstr + jg + 192]);

    float hn0 = 0.f, hn1 = 0.f, hn2 = 0.f, hn3 = 0.f;
    for (int t = 0; t < L_SEQ; t += 2) {
        SBODY(t,     0, 1, xa0, xa1, xa2, xa3)
        SBODY(t + 1, 1, 0, xb0, xb1, xb2, xb3)
    }

    if (ks == 0) {
        float* hf = out + (size_t)L_SEQ * tstr + (size_t)b * H_SZ;
        hf[jg +   0] = hn0;
        hf[jg +  64] = hn1;
        hf[jg + 128] = hn2;
        hf[jg + 192] = hn3;
    }
}

// ---------------------------------------------------------------------------
// Fused kernel: 256 blocks x 512 threads, 1 block/CU (register footprint).
// ---------------------------------------------------------------------------
__global__ __launch_bounds__(512)
__attribute__((amdgpu_waves_per_eu(2, 2)))
void rnn_fused(
    const float* __restrict__ x,  const float* __restrict__ h0,
    const float* __restrict__ Wx, const float* __restrict__ bx,
    const float* __restrict__ Wh, const float* __restrict__ bh,
    float* __restrict__ out, int* __restrict__ done)
{
    __shared__ float sA[KT][LDA];
    __shared__ float sB[KT][LDA];
    __shared__ __align__(16) float hs[2][8 * SLICE_W];

    const int bid = blockIdx.x;
    if (bid < NGEMM) {
        gemm_role(bid, x, Wx, bx, bh, out, done, sA, sB);
    } else {
        scan_role(bid - NGEMM, h0, Wh, out, done, hs);
    }
}

extern "C" void kernel_launch(void* const* d_in, const int* in_sizes, int n_in,
                              void* d_out, int out_size, void* d_ws, size_t ws_size,
                              hipStream_t stream) {
    const float* x    = (const float*)d_in[0];   // [L,B,D]
    const float* h0   = (const float*)d_in[1];   // [B,H]
    const float* Wx_w = (const float*)d_in[2];   // [H,D]
    const float* Wx_b = (const float*)d_in[3];   // [H]
    const float* Wh_w = (const float*)d_in[4];   // [H,H]
    const float* Wh_b = (const float*)d_in[5];   // [H]
    float* out = (float*)d_out;                  // [L,B,H] ++ [B,H]
    int* done = (int*)d_ws;                      // [L_SEQ] tile-completion flags

    (void)in_sizes; (void)n_in; (void)ws_size; (void)out_size;

    // Re-arm flags every iteration (graph-safe stream op).
    hipMemsetAsync(done, 0, L_SEQ * sizeof(int), stream);

    rnn_fused<<<dim3(NGEMM + NSCAN), 512, 0, stream>>>(
        x, h0, Wx_w, Wx_b, Wh_w, Wh_b, out, done);
}